// Round 1
// baseline (253.877 us; speedup 1.0000x reference)
//
#include <hip/hip_runtime.h>
#include <hip/hip_bf16.h>
#include <math.h>

// Problem constants (from reference): B=64, C=64, L=8192, fp32.
#define BB 64
#define CC 64
#define LL 8192
#define EPS_F 1.1920928955078125e-07f  // np.finfo(np.float32).eps
#define STATS_SPLITS 16                 // blocks per batch in stats kernel

// d_ws layout:
//   [0 .. 2*B)    floats : per-batch {sum, sumsq} accumulators (atomicAdd, zeroed)
//   [2*B .. 4*B)  floats : per-batch {mean, inv(std+eps)}

// ---------------------------------------------------------------------------
// Kernel 1: partial sums over the prefix data[b, :, :zp[b]].
// Grid: (B, STATS_SPLITS) x 256 threads. Block (b, s) handles rows
// c = s, s+S, ... ; threads stride over l with float4 loads.
// ---------------------------------------------------------------------------
__global__ void tln_stats(const float* __restrict__ data,
                          const int* __restrict__ zero_pos,
                          float* __restrict__ sums) {
    const int b = blockIdx.x;
    const int s = blockIdx.y;
    const int tid = threadIdx.x;           // 0..255
    const int zp = zero_pos[b];
    const int nv = zp >> 2;                // full float4's per row
    const float* base = data + (size_t)b * CC * LL;

    float sum = 0.0f, sq = 0.0f;
    for (int c = s; c < CC; c += STATS_SPLITS) {
        const float* rowp = base + (size_t)c * LL;
        const float4* row4 = (const float4*)rowp;   // L=8192 -> 16B aligned
        for (int i = tid; i < nv; i += 256) {
            float4 v = row4[i];
            sum += v.x + v.y + v.z + v.w;
            sq  += v.x * v.x + v.y * v.y + v.z * v.z + v.w * v.w;
        }
        // scalar tail (at most 3 elements)
        for (int l = (nv << 2) + tid; l < zp; l += 256) {
            float v = rowp[l];
            sum += v;
            sq  += v * v;
        }
    }

    // wave-64 butterfly reduce, then cross-wave via LDS
    #pragma unroll
    for (int off = 32; off > 0; off >>= 1) {
        sum += __shfl_down(sum, off);
        sq  += __shfl_down(sq, off);
    }
    __shared__ float lsum[4], lsq[4];
    const int wave = tid >> 6;
    const int lane = tid & 63;
    if (lane == 0) { lsum[wave] = sum; lsq[wave] = sq; }
    __syncthreads();
    if (tid == 0) {
        float ts = lsum[0] + lsum[1] + lsum[2] + lsum[3];
        float tq = lsq[0] + lsq[1] + lsq[2] + lsq[3];
        atomicAdd(&sums[2 * b],     ts);
        atomicAdd(&sums[2 * b + 1], tq);
    }
}

// ---------------------------------------------------------------------------
// Kernel 2: finalize per-batch mean and 1/(std+eps). One block, 64 threads.
// ---------------------------------------------------------------------------
__global__ void tln_finalize(const float* __restrict__ sums,
                             const int* __restrict__ zero_pos,
                             float* __restrict__ mean_inv) {
    const int b = threadIdx.x;
    if (b >= BB) return;
    const float cnt = (float)CC * (float)zero_pos[b];
    const float mean = sums[2 * b] / cnt;
    // sum((x-mean)^2) = sumsq - cnt*mean^2  (since sum(x) = cnt*mean)
    const float var = (sums[2 * b + 1] - cnt * mean * mean) / (cnt - 1.0f);
    const float stdv = sqrtf(var);
    mean_inv[2 * b]     = mean;
    mean_inv[2 * b + 1] = 1.0f / (stdv + EPS_F);
}

// ---------------------------------------------------------------------------
// Kernel 3: normalize the whole slab. One float4 per thread.
// Total vec elements: B*C*L/4 = 8388608; b = vec_idx >> 17 (C*L/4 = 2^17).
// ---------------------------------------------------------------------------
__global__ void tln_normalize(const float4* __restrict__ data,
                              const float* __restrict__ mean_inv,
                              float4* __restrict__ out) {
    const size_t i = (size_t)blockIdx.x * blockDim.x + threadIdx.x;
    const int b = (int)(i >> 17);
    const float m   = mean_inv[2 * b];
    const float inv = mean_inv[2 * b + 1];
    float4 v = data[i];
    float4 o;
    o.x = (v.x - m) * inv;
    o.y = (v.y - m) * inv;
    o.z = (v.z - m) * inv;
    o.w = (v.w - m) * inv;
    out[i] = o;
}

// ---------------------------------------------------------------------------
// Kernel 4: pass-through outputs, written as float VALUES (the harness reads
// the whole d_out buffer as float32). idxes: B*L ints -> int4/float4.
// ---------------------------------------------------------------------------
__global__ void tln_aux(const int4* __restrict__ idxes,
                        const int* __restrict__ zero_pos,
                        float4* __restrict__ out_idx,
                        float* __restrict__ out_zp) {
    const int i = blockIdx.x * blockDim.x + threadIdx.x;
    const int n4 = (BB * LL) / 4;   // 131072
    if (i < n4) {
        int4 v = idxes[i];
        float4 o;
        o.x = (float)v.x; o.y = (float)v.y; o.z = (float)v.z; o.w = (float)v.w;
        out_idx[i] = o;
    }
    if (i < BB) out_zp[i] = (float)zero_pos[i];
}

extern "C" void kernel_launch(void* const* d_in, const int* in_sizes, int n_in,
                              void* d_out, int out_size, void* d_ws, size_t ws_size,
                              hipStream_t stream) {
    const float* data    = (const float*)d_in[0];
    const int* idxes     = (const int*)d_in[1];
    const int* zero_pos  = (const int*)d_in[2];

    float* sums     = (float*)d_ws;                 // 2*B floats
    float* mean_inv = sums + 2 * BB;                // 2*B floats

    float* out_data = (float*)d_out;                        // B*C*L
    float* out_idx  = out_data + (size_t)BB * CC * LL;      // B*L
    float* out_zp   = out_idx + (size_t)BB * LL;            // B

    // zero the atomic accumulators (ws is poisoned 0xAA before every launch)
    hipMemsetAsync(d_ws, 0, 2 * BB * sizeof(float), stream);

    tln_stats<<<dim3(BB, STATS_SPLITS), 256, 0, stream>>>(data, zero_pos, sums);
    tln_finalize<<<1, 64, 0, stream>>>(sums, zero_pos, mean_inv);

    const size_t nvec = (size_t)BB * CC * LL / 4;   // 8388608
    tln_normalize<<<(unsigned)(nvec / 256), 256, 0, stream>>>(
        (const float4*)data, mean_inv, (float4*)out_data);

    const int n4 = (BB * LL) / 4;                   // 131072
    tln_aux<<<(n4 + 255) / 256, 256, 0, stream>>>(
        (const int4*)idxes, zero_pos, (float4*)out_idx, out_zp);
}

// Round 2
// 251.045 us; speedup vs baseline: 1.0113x; 1.0113x over previous
//
#include <hip/hip_runtime.h>
#include <hip/hip_bf16.h>
#include <math.h>

// Problem constants (from reference): B=64, C=64, L=8192, fp32.
#define BB 64
#define CC 64
#define LL 8192
#define EPS_F 1.1920928955078125e-07f  // np.finfo(np.float32).eps
#define SPLITS 32                       // stats blocks per batch
#define NB_NORM 32768                   // B*C*L/4/256 normalize blocks
#define NB_AUX  512                     // B*L/4/256 idx-convert blocks

// d_ws layout: partials[b][s] = float2{sum, sumsq}, 64*32 slots (16 KB).
// Every slot is written by tln_stats -> no zeroing pass, no atomics.

// ---------------------------------------------------------------------------
// Kernel 1: per-(b,s) partial {sum, sumsq} over prefix data[b, :, :zp[b]].
// Grid (B, SPLITS) x 256. Block (b,s) handles rows c = s, s+SPLITS (2 rows).
// ---------------------------------------------------------------------------
__global__ void tln_stats(const float* __restrict__ data,
                          const int* __restrict__ zero_pos,
                          float2* __restrict__ partials) {
    const int b = blockIdx.x;
    const int s = blockIdx.y;
    const int tid = threadIdx.x;           // 0..255
    const int zp = zero_pos[b];
    const int nv = zp >> 2;                // full float4's per row
    const float* base = data + (size_t)b * CC * LL;

    float sum = 0.0f, sq = 0.0f;
    for (int c = s; c < CC; c += SPLITS) {
        const float* rowp = base + (size_t)c * LL;
        const float4* row4 = (const float4*)rowp;   // L=8192 -> 16B aligned
        for (int i = tid; i < nv; i += 256) {
            float4 v = row4[i];
            sum += v.x + v.y + v.z + v.w;
            sq  += v.x * v.x + v.y * v.y + v.z * v.z + v.w * v.w;
        }
        // scalar tail (at most 3 elements)
        for (int l = (nv << 2) + tid; l < zp; l += 256) {
            float v = rowp[l];
            sum += v;
            sq  += v * v;
        }
    }

    // wave-64 reduce, then cross-wave via LDS
    #pragma unroll
    for (int off = 32; off > 0; off >>= 1) {
        sum += __shfl_down(sum, off);
        sq  += __shfl_down(sq, off);
    }
    __shared__ float lsum[4], lsq[4];
    const int wave = tid >> 6;
    const int lane = tid & 63;
    if (lane == 0) { lsum[wave] = sum; lsq[wave] = sq; }
    __syncthreads();
    if (tid == 0) {
        float2 p;
        p.x = lsum[0] + lsum[1] + lsum[2] + lsum[3];
        p.y = lsq[0] + lsq[1] + lsq[2] + lsq[3];
        partials[b * SPLITS + s] = p;
    }
}

// ---------------------------------------------------------------------------
// Kernel 2 (fused): blocks [0, NB_NORM) normalize the slab (one float4 per
// thread; each block recomputes mean/inv from the 32 L2-hot partials);
// blocks [NB_NORM, NB_NORM+NB_AUX) convert idxes->float and write zero_pos.
// ---------------------------------------------------------------------------
__global__ void tln_fused(const float4* __restrict__ data4,
                          const float2* __restrict__ partials,
                          const int* __restrict__ zero_pos,
                          const int4* __restrict__ idxes,
                          float4* __restrict__ out4,
                          float4* __restrict__ out_idx,
                          float* __restrict__ out_zp) {
    const int blk = blockIdx.x;
    const int tid = threadIdx.x;

    if (blk < NB_NORM) {
        const int b = blk >> 9;            // 512 blocks per batch (C*L/4/256)
        __shared__ float s_m, s_inv;
        if (tid < 64) {                     // wave 0 only
            float s_ = 0.0f, q_ = 0.0f;
            if (tid < SPLITS) {
                float2 p = partials[b * SPLITS + tid];
                s_ = p.x; q_ = p.y;
            }
            #pragma unroll
            for (int off = 16; off > 0; off >>= 1) {
                s_ += __shfl_down(s_, off);
                q_ += __shfl_down(q_, off);
            }
            if (tid == 0) {
                const float cnt = (float)CC * (float)zero_pos[b];
                const float mean = s_ / cnt;
                const float var = (q_ - cnt * mean * mean) / (cnt - 1.0f);
                s_m = mean;
                s_inv = 1.0f / (sqrtf(var) + EPS_F);
            }
        }
        __syncthreads();
        const float m = s_m, inv = s_inv;
        const size_t i = (size_t)blk * 256 + tid;
        float4 v = data4[i];
        float4 o;
        o.x = (v.x - m) * inv;
        o.y = (v.y - m) * inv;
        o.z = (v.z - m) * inv;
        o.w = (v.w - m) * inv;
        out4[i] = o;
    } else {
        const int j = blk - NB_NORM;
        const int i = j * 256 + tid;       // < 131072
        int4 v = idxes[i];
        float4 o;
        o.x = (float)v.x; o.y = (float)v.y; o.z = (float)v.z; o.w = (float)v.w;
        out_idx[i] = o;
        if (j == 0 && tid < BB) out_zp[tid] = (float)zero_pos[tid];
    }
}

extern "C" void kernel_launch(void* const* d_in, const int* in_sizes, int n_in,
                              void* d_out, int out_size, void* d_ws, size_t ws_size,
                              hipStream_t stream) {
    const float* data    = (const float*)d_in[0];
    const int* idxes     = (const int*)d_in[1];
    const int* zero_pos  = (const int*)d_in[2];

    float2* partials = (float2*)d_ws;       // B*SPLITS slots, all overwritten

    float* out_data = (float*)d_out;                        // B*C*L
    float* out_idx  = out_data + (size_t)BB * CC * LL;      // B*L
    float* out_zp   = out_idx + (size_t)BB * LL;            // B

    tln_stats<<<dim3(BB, SPLITS), 256, 0, stream>>>(data, zero_pos, partials);

    tln_fused<<<NB_NORM + NB_AUX, 256, 0, stream>>>(
        (const float4*)data, partials, zero_pos, (const int4*)idxes,
        (float4*)out_data, (float4*)out_idx, out_zp);
}